// Round 1
// baseline (14.097 us; speedup 1.0000x reference)
//
#include <hip/hip_runtime.h>
#include <math.h>

#define EPS_K 1e-6f

// ---------------------------------------------------------------------------
// Setup kernel: one block computes the batch-independent constants into ws:
//   ws[0..35]  : M1,M2,M3,M4 (row-major 3x3 each)
//   ws[36..39] : c1..c4
//   ws[40]     : frac_eff
//   ((int*)ws)[41], [42] : ia, ib (u time slices)
// ---------------------------------------------------------------------------
__global__ void setup_kernel(
    const float* __restrict__ t, const int* __restrict__ Dt,
    const float* __restrict__ R, const float* __restrict__ m,
    const float* __restrict__ W1, const float* __restrict__ W2,
    const float* __restrict__ W3, const float* __restrict__ W4,
    const float* __restrict__ D1, const float* __restrict__ D2,
    const float* __restrict__ D3, const float* __restrict__ D4,
    const float* __restrict__ Wb1, const float* __restrict__ Wb2,
    const float* __restrict__ Wout,
    float* __restrict__ ws, int F, int T)
{
    __shared__ float sbase[3][64];     // base[k][f] = (R@m)[k,f], F<=64
    __shared__ float sy[4][3][3];      // y[map][g][k]
    __shared__ float syo[4][3][3];     // after killing-relu
    const int tid = threadIdx.x;

    // base[k][f] = sum_j R[k,j]*m[j,f]
    for (int idx = tid; idx < 3 * F; idx += blockDim.x) {
        int k = idx / F, f = idx - k * F;
        sbase[k][f] = R[k*3+0]*m[0*F+f] + R[k*3+1]*m[1*F+f] + R[k*3+2]*m[2*F+f];
    }
    __syncthreads();

    const float* Ws[4] = {W1, W2, W3, W4};
    const float* Ds[4] = {D1, D2, D3, D4};

    // y[map][g][k] = sum_f W[g,f]*base[k][f]
    if (tid < 36) {
        int mp = tid / 9, r = tid - mp * 9;
        int g = r / 3, k = r - g * 3;
        const float* W = Ws[mp];
        float acc = 0.f;
        for (int f = 0; f < F; ++f) acc += W[g*F + f] * sbase[k][f];
        sy[mp][g][k] = acc;
    }
    __syncthreads();

    // killing relu per (map, g)
    if (tid < 12) {
        int mp = tid / 3, g = tid - mp * 3;
        const float* D = Ds[mp];
        float d0 = 0.f, d1 = 0.f, d2 = 0.f;
        for (int f = 0; f < 3; ++f) {
            float w = D[g*3 + f];
            d0 += w * sy[mp][f][0];
            d1 += w * sy[mp][f][1];
            d2 += w * sy[mp][f][2];
        }
        float y0 = sy[mp][g][0], y1 = sy[mp][g][1], y2 = sy[mp][g][2];
        float kxd = -2.f * (y0*d0 + y1*d1 + y2*d2);
        float kdd = -2.f * (d0*d0 + d1*d1 + d2*d2);
        if (kxd < 0.f) {
            syo[mp][g][0] = y0; syo[mp][g][1] = y1; syo[mp][g][2] = y2;
        } else {
            float s = kxd / (kdd - EPS_K);
            syo[mp][g][0] = y0 - s*d0; syo[mp][g][1] = y1 - s*d1; syo[mp][g][2] = y2 - s*d2;
        }
    }
    __syncthreads();

    // M[map] = m_i @ m_i^T where m_i[a][g] = syo[g][a]  =>  M[a][b] = sum_g syo[g][a]*syo[g][b]
    if (tid < 36) {
        int mp = tid / 9, r = tid - mp * 9;
        int a = r / 3, b = r - a * 3;
        float acc = 0.f;
        for (int g = 0; g < 3; ++g) acc += syo[mp][g][a] * syo[mp][g][b];
        ws[mp*9 + a*3 + b] = acc;
    } else if (tid < 40) {
        // c1..c4
        int c = tid - 36;
        const float* Wb = (c < 2) ? Wb1 : Wb2;
        const bool sq = (c == 0) || (c == 2);
        float acc = 0.f;
        for (int f = 0; f < F; ++f) {
            float w = Wb[f];
            acc += Wout[f] * (sq ? w*w : w);
        }
        ws[36 + c] = acc;
    } else if (tid == 40) {
        // interpolate_u index/frac
        float ts = t[0];
        float Df = (float)Dt[0];
        int ii = (int)floorf(ts / Df);
        if (ii < 0) ii = 0;
        if (ii > T - 1) ii = T - 1;
        float frac = (ts - (float)ii * Df) / Df;
        int ia = ii;
        int ib = (ii + 1 > T - 1) ? (T - 1) : (ii + 1);
        float frac_eff = (ii >= T - 1) ? 0.f : frac;
        ws[40] = frac_eff;
        ((int*)ws)[41] = ia;
        ((int*)ws)[42] = ib;
    }
}

// out = c1*cross(M1 x, M2 x) + c2*x + c3*cross(M3 u, M4 u) + c4*u
__device__ __forceinline__ void elem_compute(
    const float* __restrict__ M,      // 36 consts in registers
    float c1, float c2, float c3, float c4,
    float x0, float x1, float x2,
    float u0, float u1, float u2,
    float& o0, float& o1, float& o2)
{
    const float* M1 = M;      const float* M2 = M + 9;
    const float* M3 = M + 18; const float* M4 = M + 27;
    float p0 = M1[0]*x0 + M1[1]*x1 + M1[2]*x2;
    float p1 = M1[3]*x0 + M1[4]*x1 + M1[5]*x2;
    float p2 = M1[6]*x0 + M1[7]*x1 + M1[8]*x2;
    float q0 = M2[0]*x0 + M2[1]*x1 + M2[2]*x2;
    float q1 = M2[3]*x0 + M2[4]*x1 + M2[5]*x2;
    float q2 = M2[6]*x0 + M2[7]*x1 + M2[8]*x2;
    float cx0 = p1*q2 - p2*q1;
    float cx1 = p2*q0 - p0*q2;
    float cx2 = p0*q1 - p1*q0;
    float r0 = M3[0]*u0 + M3[1]*u1 + M3[2]*u2;
    float r1 = M3[3]*u0 + M3[4]*u1 + M3[5]*u2;
    float r2 = M3[6]*u0 + M3[7]*u1 + M3[8]*u2;
    float s0 = M4[0]*u0 + M4[1]*u1 + M4[2]*u2;
    float s1 = M4[3]*u0 + M4[4]*u1 + M4[5]*u2;
    float s2 = M4[6]*u0 + M4[7]*u1 + M4[8]*u2;
    float cu0 = r1*s2 - r2*s1;
    float cu1 = r2*s0 - r0*s2;
    float cu2 = r0*s1 - r1*s0;
    o0 = c1*cx0 + c2*x0 + c3*cu0 + c4*u0;
    o1 = c1*cx1 + c2*x1 + c3*cu1 + c4*u1;
    o2 = c1*cx2 + c2*x2 + c3*cu2 + c4*u2;
}

__global__ void __launch_bounds__(256) lnode_main(
    const float* __restrict__ x, const float* __restrict__ u,
    const float* __restrict__ ws, float* __restrict__ out, int B)
{
    __shared__ float s[41];
    __shared__ int si[2];
    const int tid = threadIdx.x;
    if (tid < 41) s[tid] = ws[tid];
    if (tid < 2)  si[tid] = ((const int*)ws)[41 + tid];
    __syncthreads();

    float M[36];
#pragma unroll
    for (int i = 0; i < 36; ++i) M[i] = s[i];
    const float c1 = s[36], c2 = s[37], c3 = s[38], c4 = s[39];
    const float frac = s[40];
    const float* __restrict__ ua = u + (size_t)si[0] * (size_t)B * 3u;
    const float* __restrict__ ub = u + (size_t)si[1] * (size_t)B * 3u;

    const long long gidx = (long long)blockIdx.x * blockDim.x + tid;

    if ((B & 3) == 0) {
        // vector path: 4 elements (12 floats = 3 float4) per thread
        const long long nq = (long long)(B >> 2);
        if (gidx >= nq) return;
        const float4* __restrict__ x4 = (const float4*)x;
        const float4* __restrict__ a4 = (const float4*)ua;
        const float4* __restrict__ b4 = (const float4*)ub;
        float4* __restrict__ o4 = (float4*)out;

        float4 X[3], A[3], Bv[3];
#pragma unroll
        for (int i = 0; i < 3; ++i) {
            X[i]  = x4[gidx*3 + i];
            A[i]  = a4[gidx*3 + i];
            Bv[i] = b4[gidx*3 + i];
        }
        float xf[12], uf[12], of[12];
#pragma unroll
        for (int i = 0; i < 3; ++i) {
            xf[i*4+0] = X[i].x; xf[i*4+1] = X[i].y; xf[i*4+2] = X[i].z; xf[i*4+3] = X[i].w;
            uf[i*4+0] = A[i].x + frac * (Bv[i].x - A[i].x);
            uf[i*4+1] = A[i].y + frac * (Bv[i].y - A[i].y);
            uf[i*4+2] = A[i].z + frac * (Bv[i].z - A[i].z);
            uf[i*4+3] = A[i].w + frac * (Bv[i].w - A[i].w);
        }
#pragma unroll
        for (int e = 0; e < 4; ++e) {
            elem_compute(M, c1, c2, c3, c4,
                         xf[e*3+0], xf[e*3+1], xf[e*3+2],
                         uf[e*3+0], uf[e*3+1], uf[e*3+2],
                         of[e*3+0], of[e*3+1], of[e*3+2]);
        }
#pragma unroll
        for (int i = 0; i < 3; ++i) {
            o4[gidx*3 + i] = make_float4(of[i*4+0], of[i*4+1], of[i*4+2], of[i*4+3]);
        }
    } else {
        // scalar fallback (B not multiple of 4)
        if (gidx >= B) return;
        const size_t o = (size_t)gidx * 3u;
        float x0 = x[o+0], x1 = x[o+1], x2 = x[o+2];
        float u0 = ua[o+0] + frac * (ub[o+0] - ua[o+0]);
        float u1 = ua[o+1] + frac * (ub[o+1] - ua[o+1]);
        float u2 = ua[o+2] + frac * (ub[o+2] - ua[o+2]);
        float o0, o1, o2;
        elem_compute(M, c1, c2, c3, c4, x0, x1, x2, u0, u1, u2, o0, o1, o2);
        out[o+0] = o0; out[o+1] = o1; out[o+2] = o2;
    }
}

extern "C" void kernel_launch(void* const* d_in, const int* in_sizes, int n_in,
                              void* d_out, int out_size, void* d_ws, size_t ws_size,
                              hipStream_t stream)
{
    const float* t    = (const float*)d_in[0];
    const float* x    = (const float*)d_in[1];
    const float* u    = (const float*)d_in[2];
    const int*   Dt   = (const int*)d_in[3];
    const float* R    = (const float*)d_in[4];
    const float* m    = (const float*)d_in[5];
    const float* W1   = (const float*)d_in[6];
    const float* W2   = (const float*)d_in[7];
    const float* W3   = (const float*)d_in[8];
    const float* W4   = (const float*)d_in[9];
    const float* D1   = (const float*)d_in[10];
    const float* D2   = (const float*)d_in[11];
    const float* D3   = (const float*)d_in[12];
    const float* D4   = (const float*)d_in[13];
    const float* Wb1  = (const float*)d_in[14];
    const float* Wb2  = (const float*)d_in[15];
    const float* Wout = (const float*)d_in[16];
    float* out = (float*)d_out;
    float* ws  = (float*)d_ws;

    const int B = in_sizes[1] / 3;              // x: [B,1,3]
    const int T = in_sizes[2] / in_sizes[1];    // u: [T,B,1,3]
    const int F = in_sizes[5] / 3;              // m: [3,F]

    setup_kernel<<<1, 64, 0, stream>>>(t, Dt, R, m, W1, W2, W3, W4,
                                       D1, D2, D3, D4, Wb1, Wb2, Wout, ws, F, T);

    const long long n = ((B & 3) == 0) ? (long long)B / 4 : (long long)B;
    const int blocks = (int)((n + 255) / 256);
    lnode_main<<<blocks, 256, 0, stream>>>(x, u, ws, out, B);
}

// Round 3
// 13.615 us; speedup vs baseline: 1.0354x; 1.0354x over previous
//
#include <hip/hip_runtime.h>
#include <math.h>

#define EPS_K 1e-6f

typedef float f32x4 __attribute__((ext_vector_type(4)));

// Single fused kernel. Every block redundantly computes the batch-independent
// constants (M1..M4 3x3, c1..c4) into LDS -- ~1k FLOPs, weight arrays ~1.6KB
// (L2/L3-cached after first blocks). Streaming float4 loads of x/u are issued
// BEFORE the setup barriers so HBM latency overlaps the setup chain.
//
// out[b] = c1*cross(M1 x_b, M2 x_b) + c2*x_b + c3*cross(M3 u_b, M4 u_b) + c4*u_b
// u_b = u[ia,b] + frac*(u[ib,b]-u[ia,b]),  ia/ib/frac from t,Dt (uniform).

__device__ __forceinline__ void elem_compute(
    const float* __restrict__ M,
    float c1, float c2, float c3, float c4,
    float x0, float x1, float x2,
    float u0, float u1, float u2,
    float& o0, float& o1, float& o2)
{
    const float* M1 = M;      const float* M2 = M + 9;
    const float* M3 = M + 18; const float* M4 = M + 27;
    float p0 = M1[0]*x0 + M1[1]*x1 + M1[2]*x2;
    float p1 = M1[3]*x0 + M1[4]*x1 + M1[5]*x2;
    float p2 = M1[6]*x0 + M1[7]*x1 + M1[8]*x2;
    float q0 = M2[0]*x0 + M2[1]*x1 + M2[2]*x2;
    float q1 = M2[3]*x0 + M2[4]*x1 + M2[5]*x2;
    float q2 = M2[6]*x0 + M2[7]*x1 + M2[8]*x2;
    float cx0 = p1*q2 - p2*q1;
    float cx1 = p2*q0 - p0*q2;
    float cx2 = p0*q1 - p1*q0;
    float r0 = M3[0]*u0 + M3[1]*u1 + M3[2]*u2;
    float r1 = M3[3]*u0 + M3[4]*u1 + M3[5]*u2;
    float r2 = M3[6]*u0 + M3[7]*u1 + M3[8]*u2;
    float s0 = M4[0]*u0 + M4[1]*u1 + M4[2]*u2;
    float s1 = M4[3]*u0 + M4[4]*u1 + M4[5]*u2;
    float s2 = M4[6]*u0 + M4[7]*u1 + M4[8]*u2;
    float cu0 = r1*s2 - r2*s1;
    float cu1 = r2*s0 - r0*s2;
    float cu2 = r0*s1 - r1*s0;
    o0 = c1*cx0 + c2*x0 + c3*cu0 + c4*u0;
    o1 = c1*cx1 + c2*x1 + c3*cu1 + c4*u1;
    o2 = c1*cx2 + c2*x2 + c3*cu2 + c4*u2;
}

__global__ void __launch_bounds__(256) lnode_fused(
    const float* __restrict__ t, const int* __restrict__ Dt,
    const float* __restrict__ x, const float* __restrict__ u,
    const float* __restrict__ R, const float* __restrict__ m,
    const float* __restrict__ W1, const float* __restrict__ W2,
    const float* __restrict__ W3, const float* __restrict__ W4,
    const float* __restrict__ D1, const float* __restrict__ D2,
    const float* __restrict__ D3, const float* __restrict__ D4,
    const float* __restrict__ Wb1, const float* __restrict__ Wb2,
    const float* __restrict__ Wout,
    float* __restrict__ out, int B, int T, int F)
{
    __shared__ float sbase[3][64];   // (R@m)[k][f], F<=64
    __shared__ float sy[4][3][3];
    __shared__ float syo[4][3][3];
    __shared__ float sC[40];         // 36 M + 4 c
    const int tid = threadIdx.x;

    // --- uniform interp params per-thread (scalar loads, no setup dep) ---
    const float ts  = t[0];
    const float Dtf = (float)Dt[0];
    int ii = (int)floorf(ts / Dtf);
    ii = ii < 0 ? 0 : (ii > T - 1 ? T - 1 : ii);
    const float frac = (ii >= T - 1) ? 0.f : (ts - (float)ii * Dtf) / Dtf;
    const int ibn = (ii + 1 > T - 1) ? (T - 1) : (ii + 1);

    const float* __restrict__ ua = u + (size_t)ii  * (size_t)B * 3u;
    const float* __restrict__ ub = u + (size_t)ibn * (size_t)B * 3u;

    const long long gidx = (long long)blockIdx.x * blockDim.x + tid;
    const bool vec = ((B & 3) == 0);

    // --- issue streaming loads early (overlap with setup chain) ---
    f32x4 X[3], A[3], Bv[3];
    float sx0=0, sx1=0, sx2=0, su0=0, su1=0, su2=0;
    bool active;
    if (vec) {
        const long long nq = (long long)(B >> 2);
        active = gidx < nq;
        if (active) {
            const f32x4* __restrict__ x4 = (const f32x4*)x;
            const f32x4* __restrict__ a4 = (const f32x4*)ua;
            const f32x4* __restrict__ b4 = (const f32x4*)ub;
#pragma unroll
            for (int i = 0; i < 3; ++i) {
                X[i]  = x4[gidx*3 + i];
                A[i]  = a4[gidx*3 + i];
                Bv[i] = b4[gidx*3 + i];
            }
        }
    } else {
        active = gidx < B;
        if (active) {
            const size_t o = (size_t)gidx * 3u;
            sx0 = x[o+0]; sx1 = x[o+1]; sx2 = x[o+2];
            float a0 = ua[o+0], a1 = ua[o+1], a2 = ua[o+2];
            float b0 = ub[o+0], b1 = ub[o+1], b2 = ub[o+2];
            su0 = a0 + frac*(b0-a0); su1 = a1 + frac*(b1-a1); su2 = a2 + frac*(b2-a2);
        }
    }

    // --- per-block setup chain (tiny; weights are L2/L3-cached) ---
    for (int idx = tid; idx < 3 * F; idx += blockDim.x) {
        int k = idx / F, f = idx - k * F;
        sbase[k][f] = R[k*3+0]*m[0*F+f] + R[k*3+1]*m[1*F+f] + R[k*3+2]*m[2*F+f];
    }
    __syncthreads();

    const float* Ws[4] = {W1, W2, W3, W4};
    const float* Ds[4] = {D1, D2, D3, D4};

    if (tid < 36) {
        int mp = tid / 9, r = tid - mp * 9;
        int g = r / 3, k = r - g * 3;
        const float* W = Ws[mp];
        float acc = 0.f;
        for (int f = 0; f < F; ++f) acc += W[g*F + f] * sbase[k][f];
        sy[mp][g][k] = acc;
    }
    __syncthreads();

    if (tid < 12) {
        int mp = tid / 3, g = tid - mp * 3;
        const float* D = Ds[mp];
        float d0 = 0.f, d1 = 0.f, d2 = 0.f;
        for (int f = 0; f < 3; ++f) {
            float w = D[g*3 + f];
            d0 += w * sy[mp][f][0];
            d1 += w * sy[mp][f][1];
            d2 += w * sy[mp][f][2];
        }
        float y0 = sy[mp][g][0], y1 = sy[mp][g][1], y2 = sy[mp][g][2];
        float kxd = -2.f * (y0*d0 + y1*d1 + y2*d2);
        float kdd = -2.f * (d0*d0 + d1*d1 + d2*d2);
        if (kxd < 0.f) {
            syo[mp][g][0] = y0; syo[mp][g][1] = y1; syo[mp][g][2] = y2;
        } else {
            float s = kxd / (kdd - EPS_K);
            syo[mp][g][0] = y0 - s*d0; syo[mp][g][1] = y1 - s*d1; syo[mp][g][2] = y2 - s*d2;
        }
    }
    __syncthreads();

    if (tid < 36) {
        int mp = tid / 9, r = tid - mp * 9;
        int a = r / 3, b = r - a * 3;
        float acc = 0.f;
        for (int g = 0; g < 3; ++g) acc += syo[mp][g][a] * syo[mp][g][b];
        sC[mp*9 + a*3 + b] = acc;
    } else if (tid < 40) {
        int c = tid - 36;
        const float* Wb = (c < 2) ? Wb1 : Wb2;
        const bool sq = (c == 0) || (c == 2);
        float acc = 0.f;
        for (int f = 0; f < F; ++f) {
            float w = Wb[f];
            acc += Wout[f] * (sq ? w*w : w);
        }
        sC[36 + c] = acc;
    }
    __syncthreads();

    if (!active) return;

    float M[36];
#pragma unroll
    for (int i = 0; i < 36; ++i) M[i] = sC[i];
    const float c1 = sC[36], c2 = sC[37], c3 = sC[38], c4 = sC[39];

    if (vec) {
        float xf[12], uf[12], of[12];
#pragma unroll
        for (int i = 0; i < 3; ++i) {
            xf[i*4+0] = X[i].x; xf[i*4+1] = X[i].y; xf[i*4+2] = X[i].z; xf[i*4+3] = X[i].w;
            uf[i*4+0] = A[i].x + frac * (Bv[i].x - A[i].x);
            uf[i*4+1] = A[i].y + frac * (Bv[i].y - A[i].y);
            uf[i*4+2] = A[i].z + frac * (Bv[i].z - A[i].z);
            uf[i*4+3] = A[i].w + frac * (Bv[i].w - A[i].w);
        }
#pragma unroll
        for (int e = 0; e < 4; ++e) {
            elem_compute(M, c1, c2, c3, c4,
                         xf[e*3+0], xf[e*3+1], xf[e*3+2],
                         uf[e*3+0], uf[e*3+1], uf[e*3+2],
                         of[e*3+0], of[e*3+1], of[e*3+2]);
        }
        f32x4* __restrict__ o4 = (f32x4*)out;
#pragma unroll
        for (int i = 0; i < 3; ++i) {
            f32x4 v;
            v.x = of[i*4+0]; v.y = of[i*4+1]; v.z = of[i*4+2]; v.w = of[i*4+3];
            __builtin_nontemporal_store(v, &o4[gidx*3 + i]);
        }
    } else {
        float o0, o1, o2;
        elem_compute(M, c1, c2, c3, c4, sx0, sx1, sx2, su0, su1, su2, o0, o1, o2);
        const size_t o = (size_t)gidx * 3u;
        out[o+0] = o0; out[o+1] = o1; out[o+2] = o2;
    }
}

extern "C" void kernel_launch(void* const* d_in, const int* in_sizes, int n_in,
                              void* d_out, int out_size, void* d_ws, size_t ws_size,
                              hipStream_t stream)
{
    const float* t    = (const float*)d_in[0];
    const float* x    = (const float*)d_in[1];
    const float* u    = (const float*)d_in[2];
    const int*   Dt   = (const int*)d_in[3];
    const float* R    = (const float*)d_in[4];
    const float* m    = (const float*)d_in[5];
    const float* W1   = (const float*)d_in[6];
    const float* W2   = (const float*)d_in[7];
    const float* W3   = (const float*)d_in[8];
    const float* W4   = (const float*)d_in[9];
    const float* D1   = (const float*)d_in[10];
    const float* D2   = (const float*)d_in[11];
    const float* D3   = (const float*)d_in[12];
    const float* D4   = (const float*)d_in[13];
    const float* Wb1  = (const float*)d_in[14];
    const float* Wb2  = (const float*)d_in[15];
    const float* Wout = (const float*)d_in[16];
    float* out = (float*)d_out;

    const int B = in_sizes[1] / 3;              // x: [B,1,3]
    const int T = in_sizes[2] / in_sizes[1];    // u: [T,B,1,3]
    const int F = in_sizes[5] / 3;              // m: [3,F]

    const long long n = ((B & 3) == 0) ? (long long)B / 4 : (long long)B;
    const int blocks = (int)((n + 255) / 256);

    lnode_fused<<<blocks, 256, 0, stream>>>(t, Dt, x, u, R, m,
                                            W1, W2, W3, W4, D1, D2, D3, D4,
                                            Wb1, Wb2, Wout, out, B, T, F);
}

// Round 4
// 13.400 us; speedup vs baseline: 1.0520x; 1.0160x over previous
//
#include <hip/hip_runtime.h>
#include <math.h>

#define EPS_K 1e-6f

// 12-byte element: one (x,y,z) triple. sizeof == 12 so consecutive threads
// load consecutive 12B chunks -> fully contiguous 768B per wave instruction.
struct Packed3 { float v0, v1, v2; };

// ---------------------------------------------------------------------------
// Setup kernel (1 block): batch-independent constants into ws:
//   ws[0..35]  : M1,M2,M3,M4 (row-major 3x3 each)
//   ws[36..39] : c1..c4
//   ws[40]     : frac_eff
//   ((int*)ws)[41], [42] : ia, ib (u time slices)
// ---------------------------------------------------------------------------
__global__ void setup_kernel(
    const float* __restrict__ t, const int* __restrict__ Dt,
    const float* __restrict__ R, const float* __restrict__ m,
    const float* __restrict__ W1, const float* __restrict__ W2,
    const float* __restrict__ W3, const float* __restrict__ W4,
    const float* __restrict__ D1, const float* __restrict__ D2,
    const float* __restrict__ D3, const float* __restrict__ D4,
    const float* __restrict__ Wb1, const float* __restrict__ Wb2,
    const float* __restrict__ Wout,
    float* __restrict__ ws, int F, int T)
{
    __shared__ float sbase[3][64];     // base[k][f] = (R@m)[k,f], F<=64
    __shared__ float sy[4][3][3];      // y[map][g][k]
    __shared__ float syo[4][3][3];     // after killing-relu
    const int tid = threadIdx.x;

    for (int idx = tid; idx < 3 * F; idx += blockDim.x) {
        int k = idx / F, f = idx - k * F;
        sbase[k][f] = R[k*3+0]*m[0*F+f] + R[k*3+1]*m[1*F+f] + R[k*3+2]*m[2*F+f];
    }
    __syncthreads();

    const float* Ws[4] = {W1, W2, W3, W4};
    const float* Ds[4] = {D1, D2, D3, D4};

    if (tid < 36) {
        int mp = tid / 9, r = tid - mp * 9;
        int g = r / 3, k = r - g * 3;
        const float* W = Ws[mp];
        float acc = 0.f;
#pragma unroll 4
        for (int f = 0; f < F; ++f) acc += W[g*F + f] * sbase[k][f];
        sy[mp][g][k] = acc;
    }
    __syncthreads();

    if (tid < 12) {
        int mp = tid / 3, g = tid - mp * 3;
        const float* D = Ds[mp];
        float d0 = 0.f, d1 = 0.f, d2 = 0.f;
        for (int f = 0; f < 3; ++f) {
            float w = D[g*3 + f];
            d0 += w * sy[mp][f][0];
            d1 += w * sy[mp][f][1];
            d2 += w * sy[mp][f][2];
        }
        float y0 = sy[mp][g][0], y1 = sy[mp][g][1], y2 = sy[mp][g][2];
        float kxd = -2.f * (y0*d0 + y1*d1 + y2*d2);
        float kdd = -2.f * (d0*d0 + d1*d1 + d2*d2);
        if (kxd < 0.f) {
            syo[mp][g][0] = y0; syo[mp][g][1] = y1; syo[mp][g][2] = y2;
        } else {
            float s = kxd / (kdd - EPS_K);
            syo[mp][g][0] = y0 - s*d0; syo[mp][g][1] = y1 - s*d1; syo[mp][g][2] = y2 - s*d2;
        }
    }
    __syncthreads();

    if (tid < 36) {
        int mp = tid / 9, r = tid - mp * 9;
        int a = r / 3, b = r - a * 3;
        float acc = 0.f;
        for (int g = 0; g < 3; ++g) acc += syo[mp][g][a] * syo[mp][g][b];
        ws[mp*9 + a*3 + b] = acc;
    } else if (tid < 40) {
        int c = tid - 36;
        const float* Wb = (c < 2) ? Wb1 : Wb2;
        const bool sq = (c == 0) || (c == 2);
        float acc = 0.f;
#pragma unroll 4
        for (int f = 0; f < F; ++f) {
            float w = Wb[f];
            acc += Wout[f] * (sq ? w*w : w);
        }
        ws[36 + c] = acc;
    } else if (tid == 40) {
        float ts = t[0];
        float Df = (float)Dt[0];
        int ii = (int)floorf(ts / Df);
        if (ii < 0) ii = 0;
        if (ii > T - 1) ii = T - 1;
        float frac = (ts - (float)ii * Df) / Df;
        int ia = ii;
        int ib = (ii + 1 > T - 1) ? (T - 1) : (ii + 1);
        float frac_eff = (ii >= T - 1) ? 0.f : frac;
        ws[40] = frac_eff;
        ((int*)ws)[41] = ia;
        ((int*)ws)[42] = ib;
    }
}

// ---------------------------------------------------------------------------
// Main kernel: one element per thread, 12B/lane contiguous loads/stores.
// No LDS, no barriers. Constants read as uniform (scalar) loads -> SGPRs.
// out[b] = c1*cross(M1 x_b, M2 x_b) + c2*x_b + c3*cross(M3 u_b, M4 u_b) + c4*u_b
// ---------------------------------------------------------------------------
__global__ void __launch_bounds__(256) lnode_main(
    const float* __restrict__ x, const float* __restrict__ u,
    const float* __restrict__ ws, float* __restrict__ out, int B)
{
    // uniform scalar loads of constants (compile-time indices, uniform addr)
    float M[36];
#pragma unroll
    for (int i = 0; i < 36; ++i) M[i] = ws[i];
    const float c1 = ws[36], c2 = ws[37], c3 = ws[38], c4 = ws[39];
    const float frac = ws[40];
    const int ia = ((const int*)ws)[41];
    const int ib = ((const int*)ws)[42];

    const long long idx = (long long)blockIdx.x * blockDim.x + threadIdx.x;
    if (idx >= B) return;

    const Packed3* __restrict__ xp  = (const Packed3*)x;
    const Packed3* __restrict__ uap = (const Packed3*)(u + (size_t)ia * (size_t)B * 3u);
    const Packed3* __restrict__ ubp = (const Packed3*)(u + (size_t)ib * (size_t)B * 3u);
    Packed3* __restrict__ op = (Packed3*)out;

    const Packed3 X  = xp[idx];
    const Packed3 A  = uap[idx];
    const Packed3 Bv = ubp[idx];

    const float x0 = X.v0, x1 = X.v1, x2 = X.v2;
    const float u0 = A.v0 + frac * (Bv.v0 - A.v0);
    const float u1 = A.v1 + frac * (Bv.v1 - A.v1);
    const float u2 = A.v2 + frac * (Bv.v2 - A.v2);

    const float* M1 = M;      const float* M2 = M + 9;
    const float* M3 = M + 18; const float* M4 = M + 27;
    float p0 = M1[0]*x0 + M1[1]*x1 + M1[2]*x2;
    float p1 = M1[3]*x0 + M1[4]*x1 + M1[5]*x2;
    float p2 = M1[6]*x0 + M1[7]*x1 + M1[8]*x2;
    float q0 = M2[0]*x0 + M2[1]*x1 + M2[2]*x2;
    float q1 = M2[3]*x0 + M2[4]*x1 + M2[5]*x2;
    float q2 = M2[6]*x0 + M2[7]*x1 + M2[8]*x2;
    float cx0 = p1*q2 - p2*q1;
    float cx1 = p2*q0 - p0*q2;
    float cx2 = p0*q1 - p1*q0;
    float r0 = M3[0]*u0 + M3[1]*u1 + M3[2]*u2;
    float r1 = M3[3]*u0 + M3[4]*u1 + M3[5]*u2;
    float r2 = M3[6]*u0 + M3[7]*u1 + M3[8]*u2;
    float s0 = M4[0]*u0 + M4[1]*u1 + M4[2]*u2;
    float s1 = M4[3]*u0 + M4[4]*u1 + M4[5]*u2;
    float s2 = M4[6]*u0 + M4[7]*u1 + M4[8]*u2;
    float cu0 = r1*s2 - r2*s1;
    float cu1 = r2*s0 - r0*s2;
    float cu2 = r0*s1 - r1*s0;

    Packed3 O;
    O.v0 = c1*cx0 + c2*x0 + c3*cu0 + c4*u0;
    O.v1 = c1*cx1 + c2*x1 + c3*cu1 + c4*u1;
    O.v2 = c1*cx2 + c2*x2 + c3*cu2 + c4*u2;
    op[idx] = O;
}

extern "C" void kernel_launch(void* const* d_in, const int* in_sizes, int n_in,
                              void* d_out, int out_size, void* d_ws, size_t ws_size,
                              hipStream_t stream)
{
    const float* t    = (const float*)d_in[0];
    const float* x    = (const float*)d_in[1];
    const float* u    = (const float*)d_in[2];
    const int*   Dt   = (const int*)d_in[3];
    const float* R    = (const float*)d_in[4];
    const float* m    = (const float*)d_in[5];
    const float* W1   = (const float*)d_in[6];
    const float* W2   = (const float*)d_in[7];
    const float* W3   = (const float*)d_in[8];
    const float* W4   = (const float*)d_in[9];
    const float* D1   = (const float*)d_in[10];
    const float* D2   = (const float*)d_in[11];
    const float* D3   = (const float*)d_in[12];
    const float* D4   = (const float*)d_in[13];
    const float* Wb1  = (const float*)d_in[14];
    const float* Wb2  = (const float*)d_in[15];
    const float* Wout = (const float*)d_in[16];
    float* out = (float*)d_out;
    float* ws  = (float*)d_ws;

    const int B = in_sizes[1] / 3;              // x: [B,1,3]
    const int T = in_sizes[2] / in_sizes[1];    // u: [T,B,1,3]
    const int F = in_sizes[5] / 3;              // m: [3,F]

    setup_kernel<<<1, 64, 0, stream>>>(t, Dt, R, m, W1, W2, W3, W4,
                                       D1, D2, D3, D4, Wb1, Wb2, Wout, ws, F, T);

    const int blocks = (B + 255) / 256;
    lnode_main<<<blocks, 256, 0, stream>>>(x, u, ws, out, B);
}